// Round 1
// baseline (206.184 us; speedup 1.0000x reference)
//
#include <hip/hip_runtime.h>
#include <hip/hip_bf16.h>

// GatherBlock: out[m, c, y, xw] = x[b[m], c, yb[m]*16 + y, xb[m]*16 + xw]
// N=8, C=64, H=256, W=256, BH=BW=16, M=1024. fp32.
//
// Layout (float4 units): W/4 = 64 float4 per input row; BW/4 = 4 float4 per
// block row. Each output block m = 64*16*16 floats = 4096 float4 = exactly
// 16 thread-blocks of 256 threads, one float4 per thread.
// m = blockIdx.x >> 4 is block-uniform -> index loads compile to s_load.

__global__ __launch_bounds__(256) void gather_block_kernel(
    const float4* __restrict__ x,
    const int* __restrict__ idx,
    float4* __restrict__ out) {
  const int m  = blockIdx.x >> 4;
  const int b  = idx[3 * m + 0];
  const int yb = idx[3 * m + 1];
  const int xb = idx[3 * m + 2];

  const int inner = ((blockIdx.x & 15) << 8) | threadIdx.x;  // 0..4095
  const int xw4 = inner & 3;          // float4 col within block row (0..3)
  const int y   = (inner >> 2) & 15;  // row within block (0..15)
  const int c   = inner >> 6;         // channel (0..63)

  // input address in float4 units: ((b*C + c)*H + yb*16 + y)*(W/4) + xb*4 + xw4
  const long long in4 =
      ((long long)((b << 6) + c) * 256 + (yb << 4) + y) * 64 + (xb << 2) + xw4;

  out[((long long)m << 12) + inner] = x[in4];
}

extern "C" void kernel_launch(void* const* d_in, const int* in_sizes, int n_in,
                              void* d_out, int out_size, void* d_ws, size_t ws_size,
                              hipStream_t stream) {
  const float4* x  = (const float4*)d_in[0];
  const int* idx   = (const int*)d_in[1];
  float4* out      = (float4*)d_out;

  // M * (C*BH*BW/4) / 256 = 1024 * 16 = 16384 blocks
  gather_block_kernel<<<16384, 256, 0, stream>>>(x, idx, out);
}